// Round 1
// baseline (633.841 us; speedup 1.0000x reference)
//
#include <hip/hip_runtime.h>

#define N_ROWS 262144
#define DDIM   256
#define KREF   32

typedef __attribute__((ext_vector_type(4))) float f32x4;
typedef __attribute__((ext_vector_type(8))) short bf16x8;

// Pre-packed B-operand fragment tables (written by setup_kernel, read by wy_kernel).
// Vfrag[nt][c][lane] : GEMM1 B = V[d][q], element j = Q[16nt+(lane&15)][32c+8*(lane>>4)+j]
// Ufrag[nt][lane]    : GEMM2 B = U^T,     element j = U[16nt+(lane&15)][8*(lane>>4)+j]
__device__ bf16x8 g_Vhi[2 * 8 * 64];
__device__ bf16x8 g_Vlo[2 * 8 * 64];
__device__ bf16x8 g_Uhi[16 * 64];
__device__ bf16x8 g_Ulo[16 * 64];

__device__ __forceinline__ unsigned short f2bf(float x) {
    unsigned u = __float_as_uint(x);
    u += 0x7fffu + ((u >> 16) & 1u);      // RNE
    return (unsigned short)(u >> 16);
}
__device__ __forceinline__ float bf2f(unsigned short h) {
    return __uint_as_float(((unsigned)h) << 16);
}

// ---------------------------------------------------------------------------
// Setup: beta, G = V^T V, T (larft forward), U = V T^T, and fragment packing.
// One block; runs once per launch (idempotent). Off the N-scale critical path.
// ---------------------------------------------------------------------------
__global__ __launch_bounds__(256)
void setup_kernel(const float* __restrict__ Q) {
    __shared__ float G[32 * 32];
    __shared__ float T[32 * 32];
    __shared__ float beta[32];
    __shared__ float U[256 * 32];   // [d][k]
    const int tid = threadIdx.x;

    // G[i][j] = q_i . q_j
    for (int p = tid; p < 1024; p += 256) {
        const int i = p >> 5, j = p & 31;
        const float* qi = Q + i * DDIM;
        const float* qj = Q + j * DDIM;
        float s = 0.f;
        for (int d = 0; d < DDIM; ++d) s += qi[d] * qj[d];
        G[p] = s;
    }
    __syncthreads();

    if (tid < 32) beta[tid] = 2.0f / G[tid * 32 + tid];
    for (int p = tid; p < 1024; p += 256) T[p] = 0.f;
    __syncthreads();

    // T: forward columnwise recurrence for H_1 H_2 ... H_K = I - V T V^T
    for (int k = 0; k < 32; ++k) {
        if (tid < k) {
            float s = 0.f;
            for (int j = tid; j < k; ++j) s += T[tid * 32 + j] * G[j * 32 + k];
            T[tid * 32 + k] = -beta[k] * s;
        } else if (tid == k) {
            T[k * 32 + k] = beta[k];
        }
        __syncthreads();
    }

    // U[d][k] = sum_{j>=k} T[k][j] * Q[j][d]
    for (int p = tid; p < 256 * 32; p += 256) {
        const int d = p >> 5, k = p & 31;
        float s = 0.f;
        for (int j = k; j < 32; ++j) s += T[k * 32 + j] * Q[j * DDIM + d];
        U[d * 32 + k] = s;
    }
    __syncthreads();

    // Pack V fragments (bf16 hi/lo split)
    for (int e = tid; e < 2 * 8 * 64; e += 256) {
        const int lane = e & 63, c = (e >> 6) & 7, nt = e >> 9;
        const int q  = 16 * nt + (lane & 15);
        const int d0 = 32 * c + 8 * (lane >> 4);
        bf16x8 vh, vl;
        for (int j = 0; j < 8; ++j) {
            const float x = Q[q * DDIM + d0 + j];
            const unsigned short h = f2bf(x);
            vh[j] = (short)h;
            vl[j] = (short)f2bf(x - bf2f(h));
        }
        g_Vhi[e] = vh; g_Vlo[e] = vl;
    }
    // Pack U fragments
    for (int e = tid; e < 16 * 64; e += 256) {
        const int lane = e & 63, nt = e >> 6;
        const int d  = 16 * nt + (lane & 15);
        const int k0 = 8 * (lane >> 4);
        bf16x8 uh, ul;
        for (int j = 0; j < 8; ++j) {
            const float x = U[d * 32 + k0 + j];
            const unsigned short h = f2bf(x);
            uh[j] = (short)h;
            ul[j] = (short)f2bf(x - bf2f(h));
        }
        g_Uhi[e] = uh; g_Ulo[e] = ul;
    }
}

// ---------------------------------------------------------------------------
// Main: out = X - (X V) (T V^T) via two K=32 MFMA panel GEMMs per 16-row wave.
// ---------------------------------------------------------------------------
__global__ __launch_bounds__(256)
void wy_kernel(const float* __restrict__ X, float* __restrict__ out) {
    // per-wave transpose scratch: 16 rows x stride 36 floats (bank-conflict pad)
    __shared__ float tlds[4 * 16 * 36];

    const int tid  = threadIdx.x;
    const int wave = tid >> 6;
    const int lane = tid & 63;
    const int t = lane & 15;     // A/B fragment row/col index
    const int g = lane >> 4;     // k-block index

    const size_t row0 = (size_t)blockIdx.x * 64 + wave * 16;

    // ---- Load X tile [16 x 256] in A-fragment order: X[row0+t][32c+8g+j] ----
    const float* xp = X + (row0 + t) * DDIM + 8 * g;
    f32x4 xa[16];
    #pragma unroll
    for (int c = 0; c < 8; ++c) {
        xa[2 * c]     = *(const f32x4*)(xp + 32 * c);
        xa[2 * c + 1] = *(const f32x4*)(xp + 32 * c + 4);
    }

    // ---- bf16 hi/lo split of A (X) ----
    bf16x8 ahi[8], alo[8];
    #pragma unroll
    for (int c = 0; c < 8; ++c) {
        #pragma unroll
        for (int e = 0; e < 8; ++e) {
            const float x = (e < 4) ? xa[2 * c][e] : xa[2 * c + 1][e - 4];
            const unsigned short h = f2bf(x);
            ahi[c][e] = (short)h;
            alo[c][e] = (short)f2bf(x - bf2f(h));
        }
    }

    // ---- GEMM1: C1[16x32] = X_tile . V  (3-term split, K=256 in 8 chunks) ----
    f32x4 acc0 = {0.f, 0.f, 0.f, 0.f};   // q-tile 0..15
    f32x4 acc1 = {0.f, 0.f, 0.f, 0.f};   // q-tile 16..31
    #pragma unroll
    for (int c = 0; c < 8; ++c) {
        const bf16x8 bh0 = g_Vhi[c * 64 + lane];
        const bf16x8 bl0 = g_Vlo[c * 64 + lane];
        const bf16x8 bh1 = g_Vhi[512 + c * 64 + lane];
        const bf16x8 bl1 = g_Vlo[512 + c * 64 + lane];
        acc0 = __builtin_amdgcn_mfma_f32_16x16x32_bf16(ahi[c], bh0, acc0, 0, 0, 0);
        acc0 = __builtin_amdgcn_mfma_f32_16x16x32_bf16(alo[c], bh0, acc0, 0, 0, 0);
        acc0 = __builtin_amdgcn_mfma_f32_16x16x32_bf16(ahi[c], bl0, acc0, 0, 0, 0);
        acc1 = __builtin_amdgcn_mfma_f32_16x16x32_bf16(ahi[c], bh1, acc1, 0, 0, 0);
        acc1 = __builtin_amdgcn_mfma_f32_16x16x32_bf16(alo[c], bh1, acc1, 0, 0, 0);
        acc1 = __builtin_amdgcn_mfma_f32_16x16x32_bf16(ahi[c], bl1, acc1, 0, 0, 0);
    }

    // ---- Transpose C1: D-layout (lane holds C1[4g+r][q=t,16+t]) -> A-layout ----
    float* tb = tlds + wave * (16 * 36);
    #pragma unroll
    for (int r = 0; r < 4; ++r) {
        tb[(4 * g + r) * 36 + t]      = acc0[r];
        tb[(4 * g + r) * 36 + 16 + t] = acc1[r];
    }
    asm volatile("s_waitcnt lgkmcnt(0)" ::: "memory");   // wave-private: no barrier needed
    const f32x4 c01 = *(const f32x4*)(tb + t * 36 + 8 * g);
    const f32x4 c23 = *(const f32x4*)(tb + t * 36 + 8 * g + 4);

    // negate + split: A2 = -C1  (so MFMA accumulates -C1.U^T)
    bf16x8 chi, clo;
    #pragma unroll
    for (int j = 0; j < 8; ++j) {
        const float v = -((j < 4) ? c01[j] : c23[j - 4]);
        const unsigned short h = f2bf(v);
        chi[j] = (short)h;
        clo[j] = (short)f2bf(v - bf2f(h));
    }

    // ---- GEMM2 + streaming epilogue: out = X + (-C1).U^T ----
    const float* xr = X  + row0 * DDIM;
    float*       op = out + row0 * DDIM;
    #pragma unroll
    for (int nt = 0; nt < 16; ++nt) {
        const bf16x8 bh = g_Uhi[nt * 64 + lane];
        const bf16x8 bl = g_Ulo[nt * 64 + lane];
        f32x4 a = {0.f, 0.f, 0.f, 0.f};
        a = __builtin_amdgcn_mfma_f32_16x16x32_bf16(chi, bh, a, 0, 0, 0);
        a = __builtin_amdgcn_mfma_f32_16x16x32_bf16(clo, bh, a, 0, 0, 0);
        a = __builtin_amdgcn_mfma_f32_16x16x32_bf16(chi, bl, a, 0, 0, 0);
        const int col = 16 * nt + t;
        #pragma unroll
        for (int r = 0; r < 4; ++r) {
            const int rr = 4 * g + r;
            op[rr * DDIM + col] = xr[rr * DDIM + col] + a[r];   // X reload: L2-hot
        }
    }

    // logabsdet = zeros(N), appended after N*D outputs
    if (tid < 64)
        out[(size_t)N_ROWS * DDIM + (size_t)blockIdx.x * 64 + tid] = 0.0f;
}

extern "C" void kernel_launch(void* const* d_in, const int* in_sizes, int n_in,
                              void* d_out, int out_size, void* d_ws, size_t ws_size,
                              hipStream_t stream) {
    const float* X = (const float*)d_in[0];   // [N, D] fp32
    const float* Q = (const float*)d_in[1];   // [K, D] fp32
    float* out = (float*)d_out;               // [N*D + N] fp32

    setup_kernel<<<1, 256, 0, stream>>>(Q);
    wy_kernel<<<N_ROWS / 64, 256, 0, stream>>>(X, out);
}

// Round 2
// 567.801 us; speedup vs baseline: 1.1163x; 1.1163x over previous
//
#include <hip/hip_runtime.h>

#define N_ROWS 262144
#define DDIM   256
#define KREF   32

typedef __attribute__((ext_vector_type(4))) float f32x4;
typedef __attribute__((ext_vector_type(8))) short bf16x8;

// Pre-packed B/A-operand fragment tables (written by setup_kernel).
// g_V*[nt*512 + c*64 + lane] : GEMM1 B = V, elem j = Q[16nt+(lane&15)][32c+8*(lane>>4)+j]
// g_U*[mt*64 + lane]         : GEMM2 A = U, elem j = U[16mt+(lane&15)][8*(lane>>4)+j]
__device__ bf16x8 g_Vhi[2 * 8 * 64];
__device__ bf16x8 g_Vlo[2 * 8 * 64];
__device__ bf16x8 g_Uhi[16 * 64];
__device__ bf16x8 g_Ulo[16 * 64];

__device__ __forceinline__ unsigned short f2bf(float x) {
    unsigned u = __float_as_uint(x);
    u += 0x7fffu + ((u >> 16) & 1u);      // RNE
    return (unsigned short)(u >> 16);
}
__device__ __forceinline__ float bf2f(unsigned short h) {
    return __uint_as_float(((unsigned)h) << 16);
}

// ---------------------------------------------------------------------------
// Setup: beta, G = V^T V, T (larft), U = V T^T, fragment packing.
// All heavy reads from LDS (Q staged once, coalesced). Pads kill bank conflicts.
// ---------------------------------------------------------------------------
#define QS_LD 264   // 256 + 8 floats pad  -> j*264%32 == j*8%32: 2-way max
#define T_LD  33
#define U_LD  36

__global__ __launch_bounds__(256)
void setup_kernel(const float* __restrict__ Q) {
    __shared__ float Qs[32 * QS_LD];    // 33.8 KB
    __shared__ float G[32 * 32];
    __shared__ float T[32 * T_LD];
    __shared__ float beta[32];
    __shared__ float U[256 * U_LD];     // 36.9 KB  [d][k]
    const int tid = threadIdx.x;

    // Stage Q -> LDS (padded rows), coalesced 128B per 8-thread group
    {
        const int q  = tid >> 3;        // 0..31
        const int c8 = tid & 7;
        const f32x4* src = (const f32x4*)(Q + q * DDIM);
        f32x4* dst = (f32x4*)(Qs + q * QS_LD);
        #pragma unroll
        for (int i = 0; i < 8; ++i)
            dst[c8 + 8 * i] = src[c8 + 8 * i];
    }
    __syncthreads();

    // G[i][j] = q_i . q_j   (f32x4 LDS reads; qj 2-way conflict only)
    for (int p = tid; p < 1024; p += 256) {
        const int i = p >> 5, j = p & 31;
        const f32x4* qi = (const f32x4*)(Qs + i * QS_LD);
        const f32x4* qj = (const f32x4*)(Qs + j * QS_LD);
        float s = 0.f;
        #pragma unroll 8
        for (int d = 0; d < 64; ++d) {
            const f32x4 a = qi[d], b = qj[d];
            s += a.x * b.x + a.y * b.y + a.z * b.z + a.w * b.w;
        }
        G[p] = s;
    }
    for (int p = tid; p < 32 * T_LD; p += 256) T[p] = 0.f;
    __syncthreads();

    if (tid < 32) beta[tid] = 2.0f / G[tid * 32 + tid];
    __syncthreads();

    // T: forward columnwise recurrence for H_1...H_K = I - V T V^T
    for (int k = 0; k < 32; ++k) {
        if (tid < k) {
            float s = 0.f;
            for (int j = tid; j < k; ++j) s += T[tid * T_LD + j] * G[j * 32 + k];
            T[tid * T_LD + k] = -beta[k] * s;
        } else if (tid == k) {
            T[k * T_LD + k] = beta[k];
        }
        __syncthreads();
    }

    // U[d][k] = sum_{j>=k} T[k][j] * Q[j][d]   (Qs read is broadcast per 32-lane group)
    for (int p = tid; p < 256 * 32; p += 256) {
        const int d = p >> 5, k = p & 31;
        float s = 0.f;
        for (int j = k; j < 32; ++j) s += T[k * T_LD + j] * Qs[j * QS_LD + d];
        U[d * U_LD + k] = s;
    }
    __syncthreads();

    // Pack V fragments (bf16 hi/lo split) from LDS
    for (int e = tid; e < 2 * 8 * 64; e += 256) {
        const int lane = e & 63, c = (e >> 6) & 7, nt = e >> 9;
        const int q  = 16 * nt + (lane & 15);
        const int d0 = 32 * c + 8 * (lane >> 4);
        bf16x8 vh, vl;
        #pragma unroll
        for (int j = 0; j < 8; ++j) {
            const float x = Qs[q * QS_LD + d0 + j];
            const unsigned short h = f2bf(x);
            vh[j] = (short)h;
            vl[j] = (short)f2bf(x - bf2f(h));
        }
        g_Vhi[e] = vh; g_Vlo[e] = vl;
    }
    // Pack U fragments from LDS
    for (int e = tid; e < 16 * 64; e += 256) {
        const int lane = e & 63, mt = e >> 6;
        const int d  = 16 * mt + (lane & 15);
        const int k0 = 8 * (lane >> 4);
        bf16x8 uh, ul;
        #pragma unroll
        for (int j = 0; j < 8; ++j) {
            const float x = U[d * U_LD + k0 + j];
            const unsigned short h = f2bf(x);
            uh[j] = (short)h;
            ul[j] = (short)f2bf(x - bf2f(h));
        }
        g_Uhi[e] = uh; g_Ulo[e] = ul;
    }
}

// ---------------------------------------------------------------------------
// Main: out = X - (X V)(T V^T).  GEMM1: C1 = X.V.  GEMM2 (transposed form):
// corr^T = U.(-C1^T); D-fragment = float4 of one row -> coalesced stores,
// X addend rides in the MFMA C operand.
// ---------------------------------------------------------------------------
__global__ __launch_bounds__(256)
void wy_kernel(const float* __restrict__ X, float* __restrict__ out) {
    __shared__ float tlds[4 * 16 * 36];   // per-wave transpose scratch

    const int tid  = threadIdx.x;
    const int wave = tid >> 6;
    const int lane = tid & 63;
    const int t = lane & 15;
    const int g = lane >> 4;

    const size_t row0 = (size_t)blockIdx.x * 64 + wave * 16;

    // ---- Load X tile in A-fragment order: X[row0+t][32c+8g+j] ----
    const float* xp = X + (row0 + t) * DDIM + 8 * g;
    f32x4 xa[16];
    #pragma unroll
    for (int c = 0; c < 8; ++c) {
        xa[2 * c]     = *(const f32x4*)(xp + 32 * c);
        xa[2 * c + 1] = *(const f32x4*)(xp + 32 * c + 4);
    }

    // ---- bf16 hi/lo split of A (X) ----
    bf16x8 ahi[8], alo[8];
    #pragma unroll
    for (int c = 0; c < 8; ++c) {
        #pragma unroll
        for (int e = 0; e < 8; ++e) {
            const float x = (e < 4) ? xa[2 * c][e] : xa[2 * c + 1][e - 4];
            const unsigned short h = f2bf(x);
            ahi[c][e] = (short)h;
            alo[c][e] = (short)f2bf(x - bf2f(h));
        }
    }

    // ---- GEMM1: C1[16x32] = X_tile . V  (3-term split, K=256) ----
    f32x4 acc0 = {0.f, 0.f, 0.f, 0.f};
    f32x4 acc1 = {0.f, 0.f, 0.f, 0.f};
    #pragma unroll
    for (int c = 0; c < 8; ++c) {
        const bf16x8 bh0 = g_Vhi[c * 64 + lane];
        const bf16x8 bl0 = g_Vlo[c * 64 + lane];
        const bf16x8 bh1 = g_Vhi[512 + c * 64 + lane];
        const bf16x8 bl1 = g_Vlo[512 + c * 64 + lane];
        acc0 = __builtin_amdgcn_mfma_f32_16x16x32_bf16(ahi[c], bh0, acc0, 0, 0, 0);
        acc0 = __builtin_amdgcn_mfma_f32_16x16x32_bf16(alo[c], bh0, acc0, 0, 0, 0);
        acc0 = __builtin_amdgcn_mfma_f32_16x16x32_bf16(ahi[c], bl0, acc0, 0, 0, 0);
        acc1 = __builtin_amdgcn_mfma_f32_16x16x32_bf16(ahi[c], bh1, acc1, 0, 0, 0);
        acc1 = __builtin_amdgcn_mfma_f32_16x16x32_bf16(alo[c], bh1, acc1, 0, 0, 0);
        acc1 = __builtin_amdgcn_mfma_f32_16x16x32_bf16(ahi[c], bl1, acc1, 0, 0, 0);
    }

    // ---- Early-issue epilogue X loads (independent of all compute; L2-hot) ----
    // xe[mt] = X[row0+t][16mt + 4g .. +3]  == C operand of GEMM2 tile mt
    const float* xr = X + (row0 + t) * DDIM + 4 * g;
    f32x4 xe[16];
    #pragma unroll
    for (int mt = 0; mt < 16; ++mt)
        xe[mt] = *(const f32x4*)(xr + 16 * mt);

    // ---- Transpose C1: D-layout -> B-layout fragment of -C1^T ----
    float* tb = tlds + wave * (16 * 36);
    #pragma unroll
    for (int r = 0; r < 4; ++r) {
        tb[(4 * g + r) * 36 + t]      = acc0[r];
        tb[(4 * g + r) * 36 + 16 + t] = acc1[r];
    }
    asm volatile("s_waitcnt lgkmcnt(0)" ::: "memory");   // wave-private: no barrier
    const f32x4 c01 = *(const f32x4*)(tb + t * 36 + 8 * g);
    const f32x4 c23 = *(const f32x4*)(tb + t * 36 + 8 * g + 4);

    // negate + split: fragment of -C1 (A-layout == B-layout of -C1^T, lane-identical)
    bf16x8 chi, clo;
    #pragma unroll
    for (int j = 0; j < 8; ++j) {
        const float v = -((j < 4) ? c01[j] : c23[j - 4]);
        const unsigned short h = f2bf(v);
        chi[j] = (short)h;
        clo[j] = (short)f2bf(v - bf2f(h));
    }

    // ---- GEMM2': D = U_tile.(-C1^T) + X  -> lane holds out[row t][16mt+4g..+3] ----
    float* op = out + (row0 + t) * DDIM + 4 * g;
    #pragma unroll
    for (int mt = 0; mt < 16; ++mt) {
        const bf16x8 uh = g_Uhi[mt * 64 + lane];
        const bf16x8 ul = g_Ulo[mt * 64 + lane];
        f32x4 a = xe[mt];
        a = __builtin_amdgcn_mfma_f32_16x16x32_bf16(uh, chi, a, 0, 0, 0);
        a = __builtin_amdgcn_mfma_f32_16x16x32_bf16(ul, chi, a, 0, 0, 0);
        a = __builtin_amdgcn_mfma_f32_16x16x32_bf16(uh, clo, a, 0, 0, 0);
        __builtin_nontemporal_store(a, (f32x4*)(op + 16 * mt));
    }

    // logabsdet = zeros(N)
    if (tid < 64)
        out[(size_t)N_ROWS * DDIM + (size_t)blockIdx.x * 64 + tid] = 0.0f;
}

extern "C" void kernel_launch(void* const* d_in, const int* in_sizes, int n_in,
                              void* d_out, int out_size, void* d_ws, size_t ws_size,
                              hipStream_t stream) {
    const float* X = (const float*)d_in[0];   // [N, D] fp32
    const float* Q = (const float*)d_in[1];   // [K, D] fp32
    float* out = (float*)d_out;               // [N*D + N] fp32

    setup_kernel<<<1, 256, 0, stream>>>(Q);
    wy_kernel<<<N_ROWS / 64, 256, 0, stream>>>(X, out);
}

// Round 4
// 524.009 us; speedup vs baseline: 1.2096x; 1.0836x over previous
//
#include <hip/hip_runtime.h>

#define N_ROWS 262144
#define DDIM   256
#define KREF   32
#define TILES  4                       // row-tiles (of 16 rows) per wave
#define GRID_WY (N_ROWS / (64 * TILES))   // 1024 blocks

typedef __attribute__((ext_vector_type(4))) float f32x4;
typedef __attribute__((ext_vector_type(8))) short bf16x8;

// Fragment tables (written by setup kernels).
// g_V*[nt*512 + c*64 + lane] : GEMM1 B = V, elem j = Q[16nt+(lane&15)][32c+8*(lane>>4)+j]
// g_U*[mt*64 + lane]         : GEMM2 A = U, elem j = U[16mt+(lane&15)][8*(lane>>4)+j]
__device__ bf16x8 g_Vhi[2 * 8 * 64];
__device__ bf16x8 g_Vlo[2 * 8 * 64];
__device__ bf16x8 g_Uhi[16 * 64];
__device__ bf16x8 g_Ulo[16 * 64];
__device__ float  g_T[32 * 32];

__device__ __forceinline__ unsigned short f2bf(float x) {
    unsigned u = __float_as_uint(x);
    u += 0x7fffu + ((u >> 16) & 1u);      // RNE
    return (unsigned short)(u >> 16);
}
__device__ __forceinline__ float bf2f(unsigned short h) {
    return __uint_as_float(((unsigned)h) << 16);
}

// ---------------------------------------------------------------------------
// setup_a (1 block): G = V^T V, T (larft recurrence), V fragment packing.
// ---------------------------------------------------------------------------
#define QS_LD 264
#define T_LD  33

__global__ __launch_bounds__(256)
void setup_a(const float* __restrict__ Q) {
    __shared__ float Qs[32 * QS_LD];
    __shared__ float G[32 * 32];
    __shared__ float T[32 * T_LD];
    __shared__ float beta[32];
    const int tid = threadIdx.x;

    // Stage Q -> LDS (padded rows)
    {
        const int q  = tid >> 3;
        const int c8 = tid & 7;
        const f32x4* src = (const f32x4*)(Q + q * DDIM);
        f32x4* dst = (f32x4*)(Qs + q * QS_LD);
        #pragma unroll
        for (int i = 0; i < 8; ++i)
            dst[c8 + 8 * i] = src[c8 + 8 * i];
    }
    __syncthreads();

    // G[i][j] = q_i . q_j
    for (int p = tid; p < 1024; p += 256) {
        const int i = p >> 5, j = p & 31;
        const f32x4* qi = (const f32x4*)(Qs + i * QS_LD);
        const f32x4* qj = (const f32x4*)(Qs + j * QS_LD);
        float s = 0.f;
        #pragma unroll 8
        for (int d = 0; d < 64; ++d) {
            const f32x4 a = qi[d], b = qj[d];
            s += a.x * b.x + a.y * b.y + a.z * b.z + a.w * b.w;
        }
        G[p] = s;
    }
    for (int p = tid; p < 32 * T_LD; p += 256) T[p] = 0.f;
    __syncthreads();

    if (tid < 32) beta[tid] = 2.0f / G[tid * 32 + tid];
    __syncthreads();

    // T: forward recurrence for H_1...H_K = I - V T V^T
    for (int k = 0; k < 32; ++k) {
        if (tid < k) {
            float s = 0.f;
            for (int j = tid; j < k; ++j) s += T[tid * T_LD + j] * G[j * 32 + k];
            T[tid * T_LD + k] = -beta[k] * s;
        } else if (tid == k) {
            T[k * T_LD + k] = beta[k];
        }
        __syncthreads();
    }

    // Publish T for setup_b
    for (int p = tid; p < 1024; p += 256)
        g_T[p] = T[(p >> 5) * T_LD + (p & 31)];

    // Pack V fragments (bf16 hi/lo) from Qs
    for (int e = tid; e < 2 * 8 * 64; e += 256) {
        const int lane = e & 63, c = (e >> 6) & 7, nt = e >> 9;
        const int q  = 16 * nt + (lane & 15);
        const int d0 = 32 * c + 8 * (lane >> 4);
        bf16x8 vh, vl;
        #pragma unroll
        for (int j = 0; j < 8; ++j) {
            const float x = Qs[q * QS_LD + d0 + j];
            const unsigned short h = f2bf(x);
            vh[j] = (short)h;
            vl[j] = (short)f2bf(x - bf2f(h));
        }
        g_Vhi[e] = vh; g_Vlo[e] = vl;
    }
}

// ---------------------------------------------------------------------------
// setup_b (16 blocks): U[d][k] = sum_{j>=k} T[k][j] Q[j][d] for d in block's
// 16-wide slice, then pack U fragments for that mt.
// ---------------------------------------------------------------------------
__global__ __launch_bounds__(256)
void setup_b(const float* __restrict__ Q) {
    __shared__ float Ts[32 * 32];
    __shared__ float Us[16 * 33];
    const int tid = threadIdx.x;
    const int m = blockIdx.x;          // mt = 0..15

    for (int p = tid; p < 1024; p += 256) Ts[p] = g_T[p];
    __syncthreads();

    #pragma unroll
    for (int e = 0; e < 2; ++e) {
        const int idx = tid + 256 * e;         // 0..511
        const int dd = idx >> 5, k = idx & 31;
        const int d = 16 * m + dd;
        float s = 0.f;
        for (int j = k; j < 32; ++j) s += Ts[k * 32 + j] * Q[j * DDIM + d];
        Us[dd * 33 + k] = s;
    }
    __syncthreads();

    if (tid < 64) {
        const int dd = tid & 15, k0 = 8 * (tid >> 4);
        bf16x8 uh, ul;
        #pragma unroll
        for (int j = 0; j < 8; ++j) {
            const float x = Us[dd * 33 + k0 + j];
            const unsigned short h = f2bf(x);
            uh[j] = (short)h;
            ul[j] = (short)f2bf(x - bf2f(h));
        }
        g_Uhi[m * 64 + tid] = uh;
        g_Ulo[m * 64 + tid] = ul;
    }
}

// ---------------------------------------------------------------------------
// Main: out = X - (X V)(T V^T).  Per wave: TILES row-tiles of 16, pipelined.
// V tables in LDS; U tables from L2 (16 independent mt-chunks batch-issue).
// ---------------------------------------------------------------------------
__global__ __launch_bounds__(256, 2)
void wy_kernel(const float* __restrict__ X, float* __restrict__ out) {
    __shared__ bf16x8 sVhi[1024];      // 16 KB
    __shared__ bf16x8 sVlo[1024];      // 16 KB
    __shared__ float  tscr[4 * 16 * 36];   // 9 KB transpose scratch

    const int tid  = threadIdx.x;
    const int wave = tid >> 6;
    const int lane = tid & 63;
    const int t = lane & 15;
    const int g = lane >> 4;

    // Stage V tables -> LDS
    {
        const f32x4* s1 = (const f32x4*)g_Vhi;
        const f32x4* s2 = (const f32x4*)g_Vlo;
        f32x4* d1 = (f32x4*)sVhi;
        f32x4* d2 = (f32x4*)sVlo;
        #pragma unroll
        for (int i = 0; i < 4; ++i) {
            d1[tid + 256 * i] = s1[tid + 256 * i];
            d2[tid + 256 * i] = s2[tid + 256 * i];
        }
    }
    __syncthreads();

    // This lane's A-row for tile tt: base + tt*64
    const size_t base = (size_t)blockIdx.x * (64 * TILES) + wave * 16 + t;
    float* tb = tscr + wave * (16 * 36);

    // Prologue: load tile 0's X in A-fragment order
    f32x4 xa[16];
    {
        const float* xp = X + base * DDIM + 8 * g;
        #pragma unroll
        for (int c = 0; c < 8; ++c) {
            xa[2 * c]     = *(const f32x4*)(xp + 32 * c);
            xa[2 * c + 1] = *(const f32x4*)(xp + 32 * c + 4);
        }
    }

    #pragma unroll
    for (int tt = 0; tt < TILES; ++tt) {
        const size_t row = base + (size_t)tt * 64;

        // bf16 hi/lo split of current A (frees xa for next tile)
        bf16x8 ahi[8], alo[8];
        #pragma unroll
        for (int c = 0; c < 8; ++c) {
            #pragma unroll
            for (int e = 0; e < 8; ++e) {
                const float x = (e < 4) ? xa[2 * c][e] : xa[2 * c + 1][e - 4];
                const unsigned short h = f2bf(x);
                ahi[c][e] = (short)h;
                alo[c][e] = (short)f2bf(x - bf2f(h));
            }
        }

        // Prefetch next tile's X (hides HBM latency under GEMM1+GEMM2)
        if (tt + 1 < TILES) {
            const float* xp = X + (row + 64) * DDIM + 8 * g;
            #pragma unroll
            for (int c = 0; c < 8; ++c) {
                xa[2 * c]     = *(const f32x4*)(xp + 32 * c);
                xa[2 * c + 1] = *(const f32x4*)(xp + 32 * c + 4);
            }
        }

        // GEMM1: C1 = X_tile . V ; 4 independent accumulator chains
        f32x4 a0h = {0.f, 0.f, 0.f, 0.f}, a0l = {0.f, 0.f, 0.f, 0.f};
        f32x4 a1h = {0.f, 0.f, 0.f, 0.f}, a1l = {0.f, 0.f, 0.f, 0.f};
        #pragma unroll
        for (int c = 0; c < 8; ++c) {
            const bf16x8 bh0 = sVhi[c * 64 + lane];
            const bf16x8 bl0 = sVlo[c * 64 + lane];
            const bf16x8 bh1 = sVhi[512 + c * 64 + lane];
            const bf16x8 bl1 = sVlo[512 + c * 64 + lane];
            a0h = __builtin_amdgcn_mfma_f32_16x16x32_bf16(ahi[c], bh0, a0h, 0, 0, 0);
            a0l = __builtin_amdgcn_mfma_f32_16x16x32_bf16(alo[c], bh0, a0l, 0, 0, 0);
            a0l = __builtin_amdgcn_mfma_f32_16x16x32_bf16(ahi[c], bl0, a0l, 0, 0, 0);
            a1h = __builtin_amdgcn_mfma_f32_16x16x32_bf16(ahi[c], bh1, a1h, 0, 0, 0);
            a1l = __builtin_amdgcn_mfma_f32_16x16x32_bf16(alo[c], bh1, a1l, 0, 0, 0);
            a1l = __builtin_amdgcn_mfma_f32_16x16x32_bf16(ahi[c], bl1, a1l, 0, 0, 0);
        }
        const f32x4 acc0 = a0h + a0l;
        const f32x4 acc1 = a1h + a1l;

        // Epilogue X loads (D-layout, L2-hot: same rows just read) — issue
        // before the LDS transpose so latency hides under it
        f32x4 xe[16];
        const float* xr = X + row * DDIM + 4 * g;
        #pragma unroll
        for (int mt = 0; mt < 16; ++mt)
            xe[mt] = *(const f32x4*)(xr + 16 * mt);

        // Transpose C1: D-layout -> fragment of -C1^T (wave-private scratch)
        #pragma unroll
        for (int r = 0; r < 4; ++r) {
            tb[(4 * g + r) * 36 + t]      = acc0[r];
            tb[(4 * g + r) * 36 + 16 + t] = acc1[r];
        }
        asm volatile("s_waitcnt lgkmcnt(0)" ::: "memory");
        const f32x4 c01 = *(const f32x4*)(tb + t * 36 + 8 * g);
        const f32x4 c23 = *(const f32x4*)(tb + t * 36 + 8 * g + 4);

        bf16x8 chi, clo;
        #pragma unroll
        for (int j = 0; j < 8; ++j) {
            const float v = -((j < 4) ? c01[j] : c23[j - 4]);
            const unsigned short h = f2bf(v);
            chi[j] = (short)h;
            clo[j] = (short)f2bf(v - bf2f(h));
        }

        // GEMM2': D = U_tile.(-C1^T) + X ; 16 independent chunks, U from L2
        float* op = out + row * DDIM + 4 * g;
        #pragma unroll
        for (int mt = 0; mt < 16; ++mt) {
            const bf16x8 uh = g_Uhi[mt * 64 + lane];
            const bf16x8 ul = g_Ulo[mt * 64 + lane];
            f32x4 a = xe[mt];
            a = __builtin_amdgcn_mfma_f32_16x16x32_bf16(uh, chi, a, 0, 0, 0);
            a = __builtin_amdgcn_mfma_f32_16x16x32_bf16(ul, chi, a, 0, 0, 0);
            a = __builtin_amdgcn_mfma_f32_16x16x32_bf16(uh, clo, a, 0, 0, 0);
            *(f32x4*)(op + 16 * mt) = a;
        }
    }

    // logabsdet = zeros(N): 256 rows per block, one per thread
    out[(size_t)N_ROWS * DDIM + (size_t)blockIdx.x * 256 + tid] = 0.0f;
}

extern "C" void kernel_launch(void* const* d_in, const int* in_sizes, int n_in,
                              void* d_out, int out_size, void* d_ws, size_t ws_size,
                              hipStream_t stream) {
    const float* X = (const float*)d_in[0];   // [N, D] fp32
    const float* Q = (const float*)d_in[1];   // [K, D] fp32
    float* out = (float*)d_out;               // [N*D + N] fp32

    setup_a<<<1, 256, 0, stream>>>(Q);
    setup_b<<<16, 256, 0, stream>>>(Q);
    wy_kernel<<<GRID_WY, 256, 0, stream>>>(X, out);
}

// Round 5
// 522.601 us; speedup vs baseline: 1.2129x; 1.0027x over previous
//
#include <hip/hip_runtime.h>

#define N_ROWS 262144
#define DDIM   256
#define KREF   32
#define GRID_WY (N_ROWS / 64)          // 4096 blocks, 1 tile of 16 rows per wave

typedef __attribute__((ext_vector_type(4))) float f32x4;
typedef __attribute__((ext_vector_type(8))) short bf16x8;

// Fragment tables (written by setup kernels).
// g_V*[nt*512 + c*64 + lane] : GEMM1 B = V, elem j = Q[16nt+(lane&15)][32c+8*(lane>>4)+j]
// g_U*[mt*64 + lane]         : GEMM2 A = U, elem j = U[16mt+(lane&15)][8*(lane>>4)+j]
__device__ bf16x8 g_Vhi[2 * 8 * 64];
__device__ bf16x8 g_Vlo[2 * 8 * 64];
__device__ bf16x8 g_Uhi[16 * 64];
__device__ bf16x8 g_Ulo[16 * 64];
__device__ float  g_T[32 * 32];

__device__ __forceinline__ unsigned short f2bf(float x) {
    unsigned u = __float_as_uint(x);
    u += 0x7fffu + ((u >> 16) & 1u);      // RNE
    return (unsigned short)(u >> 16);
}
__device__ __forceinline__ float bf2f(unsigned short h) {
    return __uint_as_float(((unsigned)h) << 16);
}

// ---------------------------------------------------------------------------
// setup_a (1 block): G = V^T V, T (larft recurrence), V fragment packing.
// ---------------------------------------------------------------------------
#define QS_LD 264
#define T_LD  33

__global__ __launch_bounds__(256)
void setup_a(const float* __restrict__ Q) {
    __shared__ float Qs[32 * QS_LD];
    __shared__ float G[32 * 32];
    __shared__ float T[32 * T_LD];
    __shared__ float beta[32];
    const int tid = threadIdx.x;

    // Stage Q -> LDS (padded rows)
    {
        const int q  = tid >> 3;
        const int c8 = tid & 7;
        const f32x4* src = (const f32x4*)(Q + q * DDIM);
        f32x4* dst = (f32x4*)(Qs + q * QS_LD);
        #pragma unroll
        for (int i = 0; i < 8; ++i)
            dst[c8 + 8 * i] = src[c8 + 8 * i];
    }
    __syncthreads();

    // G[i][j] = q_i . q_j
    for (int p = tid; p < 1024; p += 256) {
        const int i = p >> 5, j = p & 31;
        const f32x4* qi = (const f32x4*)(Qs + i * QS_LD);
        const f32x4* qj = (const f32x4*)(Qs + j * QS_LD);
        float s = 0.f;
        #pragma unroll 8
        for (int d = 0; d < 64; ++d) {
            const f32x4 a = qi[d], b = qj[d];
            s += a.x * b.x + a.y * b.y + a.z * b.z + a.w * b.w;
        }
        G[p] = s;
    }
    for (int p = tid; p < 32 * T_LD; p += 256) T[p] = 0.f;
    __syncthreads();

    if (tid < 32) beta[tid] = 2.0f / G[tid * 32 + tid];
    __syncthreads();

    // T: forward recurrence for H_1...H_K = I - V T V^T
    for (int k = 0; k < 32; ++k) {
        if (tid < k) {
            float s = 0.f;
            for (int j = tid; j < k; ++j) s += T[tid * T_LD + j] * G[j * 32 + k];
            T[tid * T_LD + k] = -beta[k] * s;
        } else if (tid == k) {
            T[k * T_LD + k] = beta[k];
        }
        __syncthreads();
    }

    // Publish T for setup_b
    for (int p = tid; p < 1024; p += 256)
        g_T[p] = T[(p >> 5) * T_LD + (p & 31)];

    // Pack V fragments (bf16 hi/lo) from Qs
    for (int e = tid; e < 2 * 8 * 64; e += 256) {
        const int lane = e & 63, c = (e >> 6) & 7, nt = e >> 9;
        const int q  = 16 * nt + (lane & 15);
        const int d0 = 32 * c + 8 * (lane >> 4);
        bf16x8 vh, vl;
        #pragma unroll
        for (int j = 0; j < 8; ++j) {
            const float x = Qs[q * QS_LD + d0 + j];
            const unsigned short h = f2bf(x);
            vh[j] = (short)h;
            vl[j] = (short)f2bf(x - bf2f(h));
        }
        g_Vhi[e] = vh; g_Vlo[e] = vl;
    }
}

// ---------------------------------------------------------------------------
// setup_b (16 blocks): U[d][k] = sum_{j>=k} T[k][j] Q[j][d] for d in block's
// 16-wide slice, then pack U fragments for that mt.
// ---------------------------------------------------------------------------
__global__ __launch_bounds__(256)
void setup_b(const float* __restrict__ Q) {
    __shared__ float Ts[32 * 32];
    __shared__ float Us[16 * 33];
    const int tid = threadIdx.x;
    const int m = blockIdx.x;          // mt = 0..15

    for (int p = tid; p < 1024; p += 256) Ts[p] = g_T[p];
    __syncthreads();

    #pragma unroll
    for (int e = 0; e < 2; ++e) {
        const int idx = tid + 256 * e;         // 0..511
        const int dd = idx >> 5, k = idx & 31;
        const int d = 16 * m + dd;
        float s = 0.f;
        for (int j = k; j < 32; ++j) s += Ts[k * 32 + j] * Q[j * DDIM + d];
        Us[dd * 33 + k] = s;
    }
    __syncthreads();

    if (tid < 64) {
        const int dd = tid & 15, k0 = 8 * (tid >> 4);
        bf16x8 uh, ul;
        #pragma unroll
        for (int j = 0; j < 8; ++j) {
            const float x = Us[dd * 33 + k0 + j];
            const unsigned short h = f2bf(x);
            uh[j] = (short)h;
            ul[j] = (short)f2bf(x - bf2f(h));
        }
        g_Uhi[m * 64 + tid] = uh;
        g_Ulo[m * 64 + tid] = ul;
    }
}

// ---------------------------------------------------------------------------
// Main: out = X - (X V)(T V^T). One 16-row tile per wave; lean registers.
// GEMM1 streams X per k-chunk (no xa array); GEMM2' loads xe as C-operand
// inside the mt loop (no xe array). V in LDS; U from L2.
// LDS 41 KB -> 3 blocks/CU = 12 waves/CU.
// ---------------------------------------------------------------------------
__global__ __launch_bounds__(256)
void wy_kernel(const float* __restrict__ X, float* __restrict__ out) {
    __shared__ bf16x8 sVhi[1024];      // 16 KB
    __shared__ bf16x8 sVlo[1024];      // 16 KB
    __shared__ float  tscr[4][16 * 36];   // 9 KB transpose scratch

    const int tid  = threadIdx.x;
    const int wave = tid >> 6;
    const int lane = tid & 63;
    const int t = lane & 15;
    const int g = lane >> 4;

    // Stage V tables -> LDS (coalesced f32x4)
    {
        const f32x4* s1 = (const f32x4*)g_Vhi;
        const f32x4* s2 = (const f32x4*)g_Vlo;
        f32x4* d1 = (f32x4*)sVhi;
        f32x4* d2 = (f32x4*)sVlo;
        #pragma unroll
        for (int i = 0; i < 4; ++i) {
            d1[tid + 256 * i] = s1[tid + 256 * i];
            d2[tid + 256 * i] = s2[tid + 256 * i];
        }
    }
    __syncthreads();

    const int row = blockIdx.x * 64 + wave * 16 + t;   // this lane's A-row
    const float* xp = X + (size_t)row * DDIM + 8 * g;

    // ---- GEMM1: C1 = X_tile . V, k-streamed; 4 independent acc chains ----
    f32x4 a0h = {0.f, 0.f, 0.f, 0.f}, a0l = {0.f, 0.f, 0.f, 0.f};
    f32x4 a1h = {0.f, 0.f, 0.f, 0.f}, a1l = {0.f, 0.f, 0.f, 0.f};
    #pragma unroll
    for (int c = 0; c < 8; ++c) {
        const f32x4 x0 = *(const f32x4*)(xp + 32 * c);
        const f32x4 x1 = *(const f32x4*)(xp + 32 * c + 4);
        bf16x8 ah, al;
        #pragma unroll
        for (int e = 0; e < 8; ++e) {
            const float v = (e < 4) ? x0[e] : x1[e - 4];
            const unsigned short h = f2bf(v);
            ah[e] = (short)h;
            al[e] = (short)f2bf(v - bf2f(h));
        }
        const bf16x8 bh0 = sVhi[c * 64 + lane];
        const bf16x8 bl0 = sVlo[c * 64 + lane];
        const bf16x8 bh1 = sVhi[512 + c * 64 + lane];
        const bf16x8 bl1 = sVlo[512 + c * 64 + lane];
        a0h = __builtin_amdgcn_mfma_f32_16x16x32_bf16(ah, bh0, a0h, 0, 0, 0);
        a0l = __builtin_amdgcn_mfma_f32_16x16x32_bf16(al, bh0, a0l, 0, 0, 0);
        a0l = __builtin_amdgcn_mfma_f32_16x16x32_bf16(ah, bl0, a0l, 0, 0, 0);
        a1h = __builtin_amdgcn_mfma_f32_16x16x32_bf16(ah, bh1, a1h, 0, 0, 0);
        a1l = __builtin_amdgcn_mfma_f32_16x16x32_bf16(al, bh1, a1l, 0, 0, 0);
        a1l = __builtin_amdgcn_mfma_f32_16x16x32_bf16(ah, bl1, a1l, 0, 0, 0);
    }
    const f32x4 acc0 = a0h + a0l;
    const f32x4 acc1 = a1h + a1l;

    // ---- Transpose C1: D-layout -> fragment of -C1^T (wave-private) ----
    float* tb = tscr[wave];
    #pragma unroll
    for (int r = 0; r < 4; ++r) {
        tb[(4 * g + r) * 36 + t]      = acc0[r];
        tb[(4 * g + r) * 36 + 16 + t] = acc1[r];
    }
    asm volatile("s_waitcnt lgkmcnt(0)" ::: "memory");
    __builtin_amdgcn_sched_barrier(0);
    const f32x4 c01 = *(const f32x4*)(tb + t * 36 + 8 * g);
    const f32x4 c23 = *(const f32x4*)(tb + t * 36 + 8 * g + 4);

    bf16x8 chi, clo;
    #pragma unroll
    for (int j = 0; j < 8; ++j) {
        const float v = -((j < 4) ? c01[j] : c23[j - 4]);
        const unsigned short h = f2bf(v);
        chi[j] = (short)h;
        clo[j] = (short)f2bf(v - bf2f(h));
    }

    // ---- GEMM2': D = U_tile.(-C1^T) + X ; 16 independent mt chains ----
    const float* xr = X   + (size_t)row * DDIM + 4 * g;
    float*       op = out + (size_t)row * DDIM + 4 * g;
    #pragma unroll
    for (int mt = 0; mt < 16; ++mt) {
        const f32x4 xe = *(const f32x4*)(xr + 16 * mt);   // C operand (L2-hot)
        const bf16x8 uh = g_Uhi[mt * 64 + lane];
        const bf16x8 ul = g_Ulo[mt * 64 + lane];
        f32x4 a = __builtin_amdgcn_mfma_f32_16x16x32_bf16(uh, chi, xe, 0, 0, 0);
        a = __builtin_amdgcn_mfma_f32_16x16x32_bf16(ul, chi, a, 0, 0, 0);
        a = __builtin_amdgcn_mfma_f32_16x16x32_bf16(uh, clo, a, 0, 0, 0);
        *(f32x4*)(op + 16 * mt) = a;
    }

    // logabsdet = zeros(N): 64 rows per block
    if (tid < 64)
        out[(size_t)N_ROWS * DDIM + (size_t)blockIdx.x * 64 + tid] = 0.0f;
}

extern "C" void kernel_launch(void* const* d_in, const int* in_sizes, int n_in,
                              void* d_out, int out_size, void* d_ws, size_t ws_size,
                              hipStream_t stream) {
    const float* X = (const float*)d_in[0];   // [N, D] fp32
    const float* Q = (const float*)d_in[1];   // [K, D] fp32
    float* out = (float*)d_out;               // [N*D + N] fp32

    setup_a<<<1, 256, 0, stream>>>(Q);
    setup_b<<<16, 256, 0, stream>>>(Q);
    wy_kernel<<<GRID_WY, 256, 0, stream>>>(X, out);
}